// Round 4
// baseline (57.105 us; speedup 1.0000x reference)
//
#include <hip/hip_runtime.h>
#include <hip/hip_bf16.h>

#define BB   8
#define CC   128
#define TLEN 8192
#define TBLK 32
#define NB   1024                    // blocks; 2 tiles each; 4/CU all co-resident
// d_ws layout: [0 .. 4KB)  : 1024 f32 loss partials
//              [8KB .. 40KB): W as bf16 in MFMA B-frag order
#define WS_W_OFF 8192

typedef __attribute__((ext_vector_type(8))) short short8;
typedef __attribute__((ext_vector_type(4))) float f32x4;

__device__ __forceinline__ short f2bf(float f) {
    union { float f; unsigned u; } v; v.f = f;
    return (short)((v.u + 0x7FFFu + ((v.u >> 16) & 1u)) >> 16);
}
__device__ __forceinline__ float bf2f(unsigned short h) {
    union { unsigned u; float f; } v; v.u = ((unsigned)h) << 16;
    return v.f;
}
// XOR swizzle: kills bank conflicts for BOTH t-step-4 writes and t-step-1 reads.
__device__ __forceinline__ int swz(int t, int c) {
    return c ^ (((t ^ (t >> 2)) & 7) << 3);
}

// ---- prep: W f32 [128][128] -> bf16 fragments (B operand order) ----
// lane holds W[row = dtile*16 + (lane&15)][col = ks*32 + (lane>>4)*8 + e]
__global__ void prep_w(const float* __restrict__ W, short* __restrict__ wsW) {
    const int gid   = blockIdx.x * 256 + threadIdx.x;   // 0..2047
    const int lane  = gid & 63;
    const int ksdt  = gid >> 6;                          // 0..31
    const int dtile = ksdt >> 2;
    const int ks    = ksdt & 3;
    const int row   = dtile * 16 + (lane & 15);
    const int col0  = ks * 32 + (lane >> 4) * 8;
    short8 a;
    #pragma unroll
    for (int e = 0; e < 8; ++e) a[e] = f2bf(W[row * CC + col0 + e]);
    reinterpret_cast<short8*>(wsW)[gid] = a;
}

__device__ __forceinline__ void compute_tile(
    const short (*xb)[CC], const short (*zb)[CC], const short8 (&af)[2][4],
    int wid, int r15, int q4, int tcur, int b, int pl, int xl,
    float cx, float cz, float oms, const float* __restrict__ blin,
    float* __restrict__ out, float& lsum)
{
    f32x4 aX[2][2], aZ[2][2];   // [dtile][ttile]; D layout: d=lane&15, t=q4*4+reg
    #pragma unroll
    for (int dt = 0; dt < 2; ++dt)
        #pragma unroll
        for (int tt = 0; tt < 2; ++tt) {
            aX[dt][tt] = (f32x4){0.f, 0.f, 0.f, 0.f};
            aZ[dt][tt] = (f32x4){0.f, 0.f, 0.f, 0.f};
        }

    #pragma unroll
    for (int ks = 0; ks < 4; ++ks) {
        #pragma unroll
        for (int tt = 0; tt < 2; ++tt) {
            const int tr = tt * 16 + r15;
            const int cs = swz(tr, ks * 32 + q4 * 8);
            const short8 xa = *reinterpret_cast<const short8*>(&xb[tr][cs]);
            const short8 za = *reinterpret_cast<const short8*>(&zb[tr][cs]);
            #pragma unroll
            for (int dt = 0; dt < 2; ++dt) {
                // A = data (m=t), B = W (n=d)  ->  D = out^T tile
                aX[dt][tt] = __builtin_amdgcn_mfma_f32_16x16x32_bf16(xa, af[dt][ks], aX[dt][tt], 0, 0, 0);
                aZ[dt][tt] = __builtin_amdgcn_mfma_f32_16x16x32_bf16(za, af[dt][ks], aZ[dt][tt], 0, 0, 0);
            }
        }
    }

    #pragma unroll
    for (int dt = 0; dt < 2; ++dt) {
        const int d  = wid * 32 + dt * 16 + r15;
        const float bl = blin[d];
        float* orow = out + 1 + (size_t)(b * CC + d) * TLEN;
        #pragma unroll
        for (int tt = 0; tt < 2; ++tt) {
            const int tb = tt * 16 + q4 * 4;
            #pragma unroll
            for (int j = 0; j < 4; ++j) {
                const int tl = tb + j;
                const int tg = tcur + tl;
                const float s  = cx * aX[dt][tt][j] + cz * aZ[dt][tt][j];
                const bool pm  = tg >= pl;
                const float ov = (pm ? s : 0.0f) + bl;
                const float zf = bf2f((unsigned short)zb[tl][swz(tl, d)]);
                const float w  = oms * zf;
                orow[tg] = ov + w;
                if (pm & (tg < xl)) {
                    const float xf = bf2f((unsigned short)xb[tl][swz(tl, d)]);
                    const float df = ov - (xf - w);
                    lsum += df * df;
                }
            }
        }
    }
}

__global__ __launch_bounds__(256, 4)
void cfm_main(const float* __restrict__ x1, const float* __restrict__ tsm,
              const float* __restrict__ z, const short* __restrict__ wsW,
              const float* __restrict__ blin, const int* __restrict__ xlens,
              const int* __restrict__ plens, float* __restrict__ out,
              float* __restrict__ wsPart)
{
    __shared__ short xt[2][TBLK][CC];   // swizzled bf16 tiles, double-buffered
    __shared__ short zt[2][TBLK][CC];
    __shared__ float red[4];

    const int bi = blockIdx.x;
    const int b  = bi & 7;              // consecutive t-tiles of same b land on same XCD
    const int t0 = (bi >> 3) * 64;

    const int tid  = threadIdx.x;
    const int lane = tid & 63;
    const int wid  = tid >> 6;
    const int r15  = lane & 15;
    const int q4   = lane >> 4;

    const float ts  = tsm[b];
    const int   pl  = plens[b];
    const int   xl  = xlens[b];
    const float oms = 0.999999f;        // 1 - sigma
    const float cz  = 1.0f - oms * ts;
    const float cx  = ts;

    // W fragments (B operand), pre-converted
    short8 af[2][4];
    {
        const short8* wf = reinterpret_cast<const short8*>(wsW);
        #pragma unroll
        for (int dt = 0; dt < 2; ++dt)
            #pragma unroll
            for (int ks = 0; ks < 4; ++ks)
                af[dt][ks] = wf[((wid * 2 + dt) * 4 + ks) * 64 + lane];
    }

    const int tj = (tid & 7) * 4;       // t within tile
    const int cr = tid >> 3;            // 0..31; c = p*32 + cr
    const size_t rowb = (size_t)b * CC * TLEN;

    float4 xv[4], zv[4];
    float lsum = 0.0f;

    // ---- issue loads tile 0 ----
    #pragma unroll
    for (int p = 0; p < 4; ++p) {
        const size_t g = rowb + (size_t)(p * 32 + cr) * TLEN + t0 + tj;
        xv[p] = *reinterpret_cast<const float4*>(x1 + g);
        zv[p] = *reinterpret_cast<const float4*>(z + g);
    }
    // ---- stage tile 0 -> buf 0 (swizzled, conflict-free) ----
    #pragma unroll
    for (int p = 0; p < 4; ++p) {
        const int c = p * 32 + cr;
        const float* xs = reinterpret_cast<const float*>(&xv[p]);
        const float* zs = reinterpret_cast<const float*>(&zv[p]);
        #pragma unroll
        for (int j = 0; j < 4; ++j) {
            const int t = tj + j;
            const int cs = swz(t, c);
            xt[0][t][cs] = f2bf(xs[j]);
            zt[0][t][cs] = f2bf(zs[j]);
        }
    }
    // ---- issue loads tile 1 (drain under compute 0) ----
    #pragma unroll
    for (int p = 0; p < 4; ++p) {
        const size_t g = rowb + (size_t)(p * 32 + cr) * TLEN + t0 + 32 + tj;
        xv[p] = *reinterpret_cast<const float4*>(x1 + g);
        zv[p] = *reinterpret_cast<const float4*>(z + g);
    }
    __syncthreads();

    compute_tile(xt[0], zt[0], af, wid, r15, q4, t0, b, pl, xl, cx, cz, oms, blin, out, lsum);

    // ---- stage tile 1 -> buf 1 ----
    #pragma unroll
    for (int p = 0; p < 4; ++p) {
        const int c = p * 32 + cr;
        const float* xs = reinterpret_cast<const float*>(&xv[p]);
        const float* zs = reinterpret_cast<const float*>(&zv[p]);
        #pragma unroll
        for (int j = 0; j < 4; ++j) {
            const int t = tj + j;
            const int cs = swz(t, c);
            xt[1][t][cs] = f2bf(xs[j]);
            zt[1][t][cs] = f2bf(zs[j]);
        }
    }
    __syncthreads();

    compute_tile(xt[1], zt[1], af, wid, r15, q4, t0 + 32, b, pl, xl, cx, cz, oms, blin, out, lsum);

    // ---- per-wave shuffle reduce -> per-block partial (scaled) ----
    #pragma unroll
    for (int off = 32; off >= 1; off >>= 1) lsum += __shfl_down(lsum, off);
    if (lane == 0) red[wid] = lsum;
    __syncthreads();
    if (tid == 0) {
        const float scale = 1.0f / (1024.0f * (float)(xl - pl));  // 1/(B*C*(xl-pl))
        wsPart[bi] = (red[0] + red[1] + red[2] + red[3]) * scale;
    }
}

// ---- final: sum 1024 partials -> out[0] ----
__global__ void final_red(const float* __restrict__ wsPart, float* __restrict__ out) {
    __shared__ float red[4];
    const int tid = threadIdx.x;
    float s = 0.0f;
    #pragma unroll
    for (int i = 0; i < NB / 256; ++i) s += wsPart[tid + i * 256];
    #pragma unroll
    for (int off = 32; off >= 1; off >>= 1) s += __shfl_down(s, off);
    if ((tid & 63) == 0) red[tid >> 6] = s;
    __syncthreads();
    if (tid == 0) out[0] = red[0] + red[1] + red[2] + red[3];
}

extern "C" void kernel_launch(void* const* d_in, const int* in_sizes, int n_in,
                              void* d_out, int out_size, void* d_ws, size_t ws_size,
                              hipStream_t stream) {
    const float* x1    = (const float*)d_in[0];
    // d_in[1] = mu (unused), d_in[2] = style (unused)
    const float* tsm   = (const float*)d_in[3];
    const float* z     = (const float*)d_in[4];
    const float* W     = (const float*)d_in[5];
    const float* blin  = (const float*)d_in[6];
    const int*   xlens = (const int*)d_in[7];
    const int*   plens = (const int*)d_in[8];
    float* out = (float*)d_out;

    float* wsPart = (float*)d_ws;
    short* wsW    = (short*)((char*)d_ws + WS_W_OFF);

    prep_w<<<8, 256, 0, stream>>>(W, wsW);
    cfm_main<<<NB, 256, 0, stream>>>(x1, tsm, z, wsW, blin, xlens, plens, out, wsPart);
    final_red<<<1, 256, 0, stream>>>(wsPart, out);
}

// Round 5
// 31.095 us; speedup vs baseline: 1.8365x; 1.8365x over previous
//
#include <hip/hip_runtime.h>
#include <hip/hip_bf16.h>

#define BB   8
#define CC   128
#define TLEN 8192
#define TBLK 128                     // t per block
#define NB   (BB * (TLEN / TBLK))    // 512 blocks = 2/CU
// d_ws layout: [0 .. 4KB)  : 512 f32 loss partials
//              [8KB .. 40KB): W as bf16 in MFMA A-frag order
#define WS_W_OFF 8192

typedef __attribute__((ext_vector_type(8))) short short8;
typedef __attribute__((ext_vector_type(4))) float f32x4;

__device__ __forceinline__ short f2bf(float f) {
    union { float f; unsigned u; } v; v.f = f;
    return (short)((v.u + 0x7FFFu + ((v.u >> 16) & 1u)) >> 16);
}
__device__ __forceinline__ float bf2f(unsigned short h) {
    union { unsigned u; float f; } v; v.u = ((unsigned)h) << 16;
    return v.f;
}
// Row swizzle on c-octets: bijective per row, preserves 16B frag alignment.
// h uses low t-bits (read lanes: t=T+r15) and high t-bits (write lanes: t=4a+j).
__device__ __forceinline__ int swz(int t, int c) {
    return c ^ (((t ^ (t >> 3)) & 15) << 3);
}

// ---- prep: W f32 [128][128] -> bf16 fragments (A operand order) ----
// dtile 0..7: lane holds W[row = dtile*16 + (lane&15)][col = ks*32 + (lane>>4)*8 + e]
__global__ void prep_w(const float* __restrict__ W, short* __restrict__ wsW) {
    const int gid   = blockIdx.x * 256 + threadIdx.x;   // 0..2047
    const int lane  = gid & 63;
    const int ksdt  = gid >> 6;                          // 0..31
    const int dtile = ksdt >> 2;
    const int ks    = ksdt & 3;
    const int row   = dtile * 16 + (lane & 15);
    const int col0  = ks * 32 + (lane >> 4) * 8;
    short8 a;
    #pragma unroll
    for (int e = 0; e < 8; ++e) a[e] = f2bf(W[row * CC + col0 + e]);
    reinterpret_cast<short8*>(wsW)[gid] = a;
}

__global__ __launch_bounds__(512, 4)
void cfm_main(const float* __restrict__ x1, const float* __restrict__ tsm,
              const float* __restrict__ z, const short* __restrict__ wsW,
              const float* __restrict__ blin, const int* __restrict__ xlens,
              const int* __restrict__ plens, float* __restrict__ out,
              float* __restrict__ wsPart)
{
    __shared__ short xt[TBLK][CC];   // bf16 [t][c], swizzled rows (256B each)
    __shared__ short zt[TBLK][CC];
    __shared__ float red[8];

    const int bi = blockIdx.x;
    const int b  = bi & 7;
    const int t0 = (bi >> 3) * TBLK;

    const int tid  = threadIdx.x;
    const int lane = tid & 63;
    const int wid  = tid >> 6;          // 0..7
    const int r15  = lane & 15;
    const int q4   = lane >> 4;

    const float ts  = tsm[b];
    const int   pl  = plens[b];
    const int   xl  = xlens[b];
    const float oms = 0.999999f;        // 1 - sigma
    const float cz  = 1.0f - oms * ts;
    const float cx  = ts;

    // ---- issue ALL 16 global float4 loads up front (512B/row spans) ----
    const int tpart = (tid & 31) * 4;   // local t base
    const int c0    = tid >> 5;         // 0..15
    const size_t rowb = (size_t)b * CC * TLEN + (size_t)t0 + tpart;

    float4 xv[8], zv[8];
    #pragma unroll
    for (int p = 0; p < 8; ++p)
        xv[p] = *reinterpret_cast<const float4*>(x1 + rowb + (size_t)(c0 + p * 16) * TLEN);
    #pragma unroll
    for (int p = 0; p < 8; ++p)
        zv[p] = *reinterpret_cast<const float4*>(z + rowb + (size_t)(c0 + p * 16) * TLEN);

    // A fragments (W), L2-hot, overlaps with load drain
    short8 af[4];
    {
        const short8* wf = reinterpret_cast<const short8*>(wsW);
        #pragma unroll
        for (int ks = 0; ks < 4; ++ks)
            af[ks] = wf[(wid * 4 + ks) * 64 + lane];
    }

    // ---- stage: transpose + cvt into swizzled bf16 tiles ----
    #pragma unroll
    for (int p = 0; p < 8; ++p) {
        const int c = c0 + p * 16;
        const float* xs = reinterpret_cast<const float*>(&xv[p]);
        const float* zs = reinterpret_cast<const float*>(&zv[p]);
        #pragma unroll
        for (int j = 0; j < 4; ++j) {
            const int t  = tpart + j;
            const int cs = swz(t, c);
            xt[t][cs] = f2bf(xs[j]);
            zt[t][cs] = f2bf(zs[j]);
        }
    }
    __syncthreads();

    // ---- MFMA: out tile [128 d][128 t]; wave w owns d in [16w, 16w+16) ----
    f32x4 aX[8], aZ[8];
    #pragma unroll
    for (int tt = 0; tt < 8; ++tt) { aX[tt] = (f32x4){0,0,0,0}; aZ[tt] = (f32x4){0,0,0,0}; }

    #pragma unroll
    for (int ks = 0; ks < 4; ++ks) {
        #pragma unroll
        for (int tt = 0; tt < 8; ++tt) {
            const int tr = tt * 16 + r15;
            const int cs = swz(tr, ks * 32 + q4 * 8);
            const short8 xa = *reinterpret_cast<const short8*>(&xt[tr][cs]);
            const short8 za = *reinterpret_cast<const short8*>(&zt[tr][cs]);
            aX[tt] = __builtin_amdgcn_mfma_f32_16x16x32_bf16(af[ks], xa, aX[tt], 0, 0, 0);
            aZ[tt] = __builtin_amdgcn_mfma_f32_16x16x32_bf16(af[ks], za, aZ[tt], 0, 0, 0);
        }
    }

    // ---- epilogue: D layout col(t)=lane&15, row(d)=q4*4+reg ----
    float lsum = 0.0f;
    #pragma unroll
    for (int rr = 0; rr < 4; ++rr) {
        const int d  = wid * 16 + q4 * 4 + rr;
        const float bl = blin[d];
        float* orow = out + 1 + (size_t)(b * CC + d) * TLEN + t0;
        #pragma unroll
        for (int tt = 0; tt < 8; ++tt) {
            const int tl = tt * 16 + r15;
            const int tg = t0 + tl;
            const float s  = cx * aX[tt][rr] + cz * aZ[tt][rr];
            const bool pm  = tg >= pl;
            const float ov = (pm ? s : 0.0f) + bl;
            const int cs   = swz(tl, d);
            const float w  = oms * bf2f((unsigned short)zt[tl][cs]);
            orow[tl] = ov + w;
            if (pm & (tg < xl)) {
                const float xf = bf2f((unsigned short)xt[tl][cs]);
                const float df = ov - (xf - w);
                lsum += df * df;
            }
        }
    }

    // ---- per-wave shuffle reduce -> per-block partial (scaled) ----
    #pragma unroll
    for (int off = 32; off >= 1; off >>= 1) lsum += __shfl_down(lsum, off);
    if (lane == 0) red[wid] = lsum;
    __syncthreads();
    if (tid == 0) {
        const float scale = 1.0f / (1024.0f * (float)(xl - pl));  // 1/(B*C*(xl-pl))
        float s = 0.0f;
        #pragma unroll
        for (int w = 0; w < 8; ++w) s += red[w];
        wsPart[bi] = s * scale;
    }
}

// ---- final: sum 512 partials -> out[0] ----
__global__ void final_red(const float* __restrict__ wsPart, float* __restrict__ out) {
    __shared__ float red[4];
    const int tid = threadIdx.x;
    float s = 0.0f;
    #pragma unroll
    for (int i = 0; i < NB / 256; ++i) s += wsPart[tid + i * 256];
    #pragma unroll
    for (int off = 32; off >= 1; off >>= 1) s += __shfl_down(s, off);
    if ((tid & 63) == 0) red[tid >> 6] = s;
    __syncthreads();
    if (tid == 0) out[0] = red[0] + red[1] + red[2] + red[3];
}

extern "C" void kernel_launch(void* const* d_in, const int* in_sizes, int n_in,
                              void* d_out, int out_size, void* d_ws, size_t ws_size,
                              hipStream_t stream) {
    const float* x1    = (const float*)d_in[0];
    // d_in[1] = mu (unused), d_in[2] = style (unused)
    const float* tsm   = (const float*)d_in[3];
    const float* z     = (const float*)d_in[4];
    const float* W     = (const float*)d_in[5];
    const float* blin  = (const float*)d_in[6];
    const int*   xlens = (const int*)d_in[7];
    const int*   plens = (const int*)d_in[8];
    float* out = (float*)d_out;

    float* wsPart = (float*)d_ws;
    short* wsW    = (short*)((char*)d_ws + WS_W_OFF);

    prep_w<<<8, 256, 0, stream>>>(W, wsW);
    cfm_main<<<NB, 512, 0, stream>>>(x1, tsm, z, wsW, blin, xlens, plens, out, wsPart);
    final_red<<<1, 256, 0, stream>>>(wsPart, out);
}